// Round 1
// baseline (244.091 us; speedup 1.0000x reference)
//
#include <hip/hip_runtime.h>
#include <hip/hip_bf16.h>
#include <cstdint>

// Problem: out = inputs @ W  (softmax over a constant axis is uniform; GAT collapses to the GEMM)
// inputs: (131072, 256) fp32, W: (256,256) fp32, out: (131072, 256) fp32.

static constexpr int MTOT = 64 * 2048;   // 131072
static constexpr int KDIM = 256;
static constexpr int NDIM = 256;

typedef __bf16 bf16x8 __attribute__((ext_vector_type(8)));
typedef float f32x4 __attribute__((ext_vector_type(4)));

__device__ __forceinline__ uint32_t f2bf_pk(float a, float b) {
    // pack two fp32 -> two bf16 (RNE), lo = a, hi = b
    uint32_t ua = __float_as_uint(a);
    uint32_t ub = __float_as_uint(b);
    ua = ua + 0x7fffu + ((ua >> 16) & 1u);
    ub = ub + 0x7fffu + ((ub >> 16) & 1u);
    return (ua >> 16) | (ub & 0xffff0000u);
}

// --- kernel 1: W (k-major fp32) -> Wt (n-major bf16) in workspace -----------
__global__ void wt_transpose(const float* __restrict__ W, unsigned short* __restrict__ Wt) {
    int n = blockIdx.x;    // 256 blocks
    int k = threadIdx.x;   // 256 threads
    float v = W[k * NDIM + n];           // uncoalesced read; W is 256 KB, L2 absorbs
    uint32_t u = __float_as_uint(v);
    u = u + 0x7fffu + ((u >> 16) & 1u);
    Wt[n * KDIM + k] = (unsigned short)(u >> 16);   // coalesced write
}

// --- kernel 2: main GEMM -----------------------------------------------------
// BM=128, BN=256 (full N -> inputs read exactly once), BK=64, 512 threads = 8 waves (2x4),
// each wave 64x64 via 4x4 tiles of mfma_f32_16x16x32_bf16.
__global__ __launch_bounds__(512, 4)
void gat_gemm(const float* __restrict__ A, const unsigned short* __restrict__ Wt,
              float* __restrict__ C) {
    // padded rows: 72 bf16 = 144 B (16B-aligned, breaks bank aliasing)
    __shared__ alignas(16) unsigned short As[128 * 72];   // 18 KB
    __shared__ alignas(16) unsigned short Bs[256 * 72];   // 36 KB

    const int tid  = threadIdx.x;
    const int lane = tid & 63;
    const int wave = tid >> 6;
    const int l15  = lane & 15;
    const int quad = lane >> 4;
    const int wm   = wave >> 2;      // 0..1  (M)
    const int wn   = wave & 3;       // 0..3  (N)

    const int bm = blockIdx.x * 128;

    // staging coords
    const int arow = tid >> 2;       // 0..127 (A row within tile)
    const int aseg = tid & 3;        // 0..3   (16-float segment)
    const int brow = tid >> 3;       // 0..63  (Wt row)
    const int bseg = tid & 7;        // 0..7   (16-byte segment)

    f32x4 acc[4][4];
#pragma unroll
    for (int i = 0; i < 4; ++i)
#pragma unroll
        for (int j = 0; j < 4; ++j)
            acc[i][j] = (f32x4)0.0f;

    for (int kt = 0; kt < 4; ++kt) {
        const int k0 = kt * 64;

        // ---- global loads first (overlap latency with prior compute tail) ----
        const float4* ap = (const float4*)(A + (size_t)(bm + arow) * KDIM + k0 + aseg * 16);
        float4 a0 = ap[0], a1 = ap[1], a2 = ap[2], a3 = ap[3];

        const unsigned short* bp = Wt + (size_t)brow * KDIM + k0 + bseg * 8;
        uint4 b0 = *(const uint4*)(bp);
        uint4 b1 = *(const uint4*)(bp + 64 * KDIM);
        uint4 b2 = *(const uint4*)(bp + 128 * KDIM);
        uint4 b3 = *(const uint4*)(bp + 192 * KDIM);

        if (kt) __syncthreads();   // prior iter's LDS reads done

        // ---- A: convert fp32->bf16, 2x ds_write_b128 ----
        {
            uint4 w0, w1;
            w0.x = f2bf_pk(a0.x, a0.y); w0.y = f2bf_pk(a0.z, a0.w);
            w0.z = f2bf_pk(a1.x, a1.y); w0.w = f2bf_pk(a1.z, a1.w);
            w1.x = f2bf_pk(a2.x, a2.y); w1.y = f2bf_pk(a2.z, a2.w);
            w1.z = f2bf_pk(a3.x, a3.y); w1.w = f2bf_pk(a3.z, a3.w);
            uint4* dst = (uint4*)&As[arow * 72 + aseg * 16];
            dst[0] = w0;
            dst[1] = w1;
        }
        // ---- B: already bf16, 4x ds_write_b128 ----
        *(uint4*)&Bs[(brow +   0) * 72 + bseg * 8] = b0;
        *(uint4*)&Bs[(brow +  64) * 72 + bseg * 8] = b1;
        *(uint4*)&Bs[(brow + 128) * 72 + bseg * 8] = b2;
        *(uint4*)&Bs[(brow + 192) * 72 + bseg * 8] = b3;

        __syncthreads();

        // ---- MFMA over BK=64 (2 k-steps of 32) ----
#pragma unroll
        for (int ks = 0; ks < 2; ++ks) {
            bf16x8 af[4];
#pragma unroll
            for (int i = 0; i < 4; ++i)
                af[i] = *(const bf16x8*)&As[(wm * 64 + i * 16 + l15) * 72 + ks * 32 + quad * 8];
#pragma unroll
            for (int j = 0; j < 4; ++j) {
                bf16x8 bfj = *(const bf16x8*)&Bs[(wn * 64 + j * 16 + l15) * 72 + ks * 32 + quad * 8];
#pragma unroll
                for (int i = 0; i < 4; ++i)
                    acc[i][j] = __builtin_amdgcn_mfma_f32_16x16x32_bf16(af[i], bfj, acc[i][j], 0, 0, 0);
            }
        }
    }

    // ---- epilogue: C/D layout col=lane&15, row=quad*4+r ----
#pragma unroll
    for (int i = 0; i < 4; ++i) {
#pragma unroll
        for (int j = 0; j < 4; ++j) {
            const int n = wn * 64 + j * 16 + l15;
            const size_t mbase = (size_t)(bm + wm * 64 + i * 16 + quad * 4);
#pragma unroll
            for (int r = 0; r < 4; ++r)
                C[(mbase + r) * NDIM + n] = acc[i][j][r];
        }
    }
}

extern "C" void kernel_launch(void* const* d_in, const int* in_sizes, int n_in,
                              void* d_out, int out_size, void* d_ws, size_t ws_size,
                              hipStream_t stream) {
    (void)in_sizes; (void)n_in; (void)out_size; (void)ws_size;
    const float* inputs = (const float*)d_in[0];
    const float* W      = (const float*)d_in[1];
    // d_in[2] ('a') is mathematically unused: softmax over a constant axis is uniform,
    // so the output is exactly inputs @ W.
    unsigned short* Wt = (unsigned short*)d_ws;     // 256*256*2 = 128 KB scratch
    float* out = (float*)d_out;

    hipLaunchKernelGGL(wt_transpose, dim3(NDIM), dim3(KDIM), 0, stream, W, Wt);
    hipLaunchKernelGGL(gat_gemm, dim3(MTOT / 128), dim3(512), 0, stream, inputs, Wt, out);
}